// Round 1
// baseline (748.377 us; speedup 1.0000x reference)
//
#include <hip/hip_runtime.h>
#include <math.h>

// Problem constants (from setup_inputs): B=4, C=64, H=128, W=128, K=9, O=64
#define HWPIX 16384   // H*W

__device__ __forceinline__ float fast_tanh(float a) {
    float aa = fabsf(a);
    float e = __expf(2.f * aa);
    float t = 1.f - 2.f / (e + 1.f);   // e==inf -> t = 1
    return copysignf(t, a);
}

// ---------------------------------------------------------------------------
// Kernel 1: fused 3x3 conv (off) + 5x5 conv (theta), raw outputs + GN stats.
// grid (8,8,4), block 256 (16x16 tile of output pixels).
// ---------------------------------------------------------------------------
__global__ __launch_bounds__(256) void k_conv(
    const float* __restrict__ x,
    const float* __restrict__ w_off, const float* __restrict__ b_off,
    const float* __restrict__ w_th,  const float* __restrict__ b_th,
    float* __restrict__ off_raw, float* __restrict__ th_raw,
    float* __restrict__ stats)
{
    __shared__ float tile[20][20];
    const int t  = threadIdx.x;
    const int tx = t & 15, ty = t >> 4;
    const int b  = blockIdx.z;
    const int h0 = blockIdx.y << 4, w0 = blockIdx.x << 4;

    float accO[9], accT[9];
#pragma unroll
    for (int k = 0; k < 9; ++k) { accO[k] = 0.f; accT[k] = 0.f; }

    for (int c = 0; c < 64; ++c) {
        __syncthreads();
        const float* xp = x + (((b << 6) + c) << 14);
        for (int e = t; e < 400; e += 256) {
            int r = e / 20, cc = e - r * 20;
            int hh = h0 + r - 2, ww = w0 + cc - 2;
            tile[r][cc] = (hh >= 0 && hh < 128 && ww >= 0 && ww < 128)
                            ? xp[(hh << 7) + ww] : 0.f;
        }
        __syncthreads();

        float win[5][5];
#pragma unroll
        for (int i = 0; i < 5; ++i)
#pragma unroll
            for (int j = 0; j < 5; ++j)
                win[i][j] = tile[ty + i][tx + j];

#pragma unroll
        for (int k = 0; k < 9; ++k) {
            const float* wo = w_off + (size_t)((k << 6) + c) * 9;
            float a = accO[k];
#pragma unroll
            for (int i = 0; i < 3; ++i)
#pragma unroll
                for (int j = 0; j < 3; ++j)
                    a = fmaf(win[i + 1][j + 1], wo[i * 3 + j], a);
            accO[k] = a;

            const float* wt = w_th + (size_t)((k << 6) + c) * 25;
            float bb = accT[k];
#pragma unroll
            for (int i = 0; i < 5; ++i)
#pragma unroll
                for (int j = 0; j < 5; ++j)
                    bb = fmaf(win[i][j], wt[i * 5 + j], bb);
            accT[k] = bb;
        }
    }

    const int h = h0 + ty, w = w0 + tx;
    const int pix = (h << 7) + w;
#pragma unroll
    for (int k = 0; k < 9; ++k) {
        float v = accO[k] + b_off[k];
        off_raw[((b * 9 + k) << 14) + pix] = v;
        float s1 = v, s2 = v * v;
#pragma unroll
        for (int d = 32; d; d >>= 1) { s1 += __shfl_down(s1, d, 64); s2 += __shfl_down(s2, d, 64); }
        if ((t & 63) == 0) {
            atomicAdd(&stats[b * 9 + k], s1);
            atomicAdd(&stats[36 + b * 9 + k], s2);
        }
        float u = accT[k] + b_th[k];
        th_raw[((b * 9 + k) << 14) + pix] = u;
        s1 = u; s2 = u * u;
#pragma unroll
        for (int d = 32; d; d >>= 1) { s1 += __shfl_down(s1, d, 64); s2 += __shfl_down(s2, d, 64); }
        if ((t & 63) == 0) {
            atomicAdd(&stats[72 + b * 9 + k], s1);
            atomicAdd(&stats[108 + b * 9 + k], s2);
        }
    }
}

// ---------------------------------------------------------------------------
// Kernel 2: deformable bilinear sample + strip contraction (sum over c,k) +
// output GN stats. grid 1024 (= B * 256), block 256.
// Each block: 64 pixels (half a row). 4 waves each cover 16 channels (phase 1)
// and 16 output channels stride-4 (phase 2).
// ---------------------------------------------------------------------------
__global__ __launch_bounds__(256) void k_sample_strip(
    const float* __restrict__ x,
    const float* __restrict__ off_raw, const float* __restrict__ th_raw,
    const float* __restrict__ stats,
    const float* __restrict__ g_off, const float* __restrict__ be_off,
    const float* __restrict__ g_th,  const float* __restrict__ be_th,
    const float* __restrict__ w_strip, const float* __restrict__ b_strip,
    float* __restrict__ out, float* __restrict__ out_stats)
{
    __shared__ float dsm[64][65];
    const int t    = threadIdx.x;
    const int lane = t & 63;
    const int wv   = __builtin_amdgcn_readfirstlane(t >> 6);  // force SGPR: wave-uniform
    const int blk  = blockIdx.x;
    const int b    = blk >> 8;
    const int p    = ((blk & 255) << 6) + lane;
    const int h    = p >> 7, w = p & 127;

    // GroupNorm stats for off/theta (redundant per thread; tiny)
    float muO[3], isO[3], muT[3], isT[3];
    const float inv_cnt = 1.f / (3.f * 16384.f);
#pragma unroll
    for (int g = 0; g < 3; ++g) {
        float s = 0.f, q = 0.f;
#pragma unroll
        for (int j = 0; j < 3; ++j) { s += stats[b * 9 + 3 * g + j]; q += stats[36 + b * 9 + 3 * g + j]; }
        float mu = s * inv_cnt;
        muO[g] = mu; isO[g] = rsqrtf(fmaxf(q * inv_cnt - mu * mu, 0.f) + 1e-5f);
        s = 0.f; q = 0.f;
#pragma unroll
        for (int j = 0; j < 3; ++j) { s += stats[72 + b * 9 + 3 * g + j]; q += stats[108 + b * 9 + 3 * g + j]; }
        mu = s * inv_cnt;
        muT[g] = mu; isT[g] = rsqrtf(fmaxf(q * inv_cnt - mu * mu, 0.f) + 1e-5f);
    }

    float acc[16];
#pragma unroll
    for (int i = 0; i < 16; ++i) acc[i] = 0.f;

    for (int k = 0; k < 9; ++k) {
        const int s = k - 4;
        const int m = 4 + (s < 0 ? -s : s);
        float yy, xx;
        if (k == 4) {
            yy = (float)h; xx = (float)w;
        } else {
            const int g = m / 3;
            float z = (th_raw[((b * 9 + m) << 14) + p] - muT[g]) * isT[g] * g_th[m] + be_th[m];
            float f = fast_tanh((off_raw[((b * 9 + m) << 14) + p] - muO[g]) * isO[g] * g_off[m] + be_off[m]);
            float r = rsqrtf(1.f + z * z);     // cos(arctan z); sin = z*r; tan = z
            float fs = (float)s;
            yy = (float)h + fs + (fs * z + f * r);
            xx = (float)w + fs + (fs - z * r * f);
            yy = fminf(fmaxf(yy, 0.f), 127.f);
            xx = fminf(fmaxf(xx, 0.f), 127.f);
        }
        float y0f = floorf(yy), x0f = floorf(xx);
        float wy = yy - y0f, wx = xx - x0f;
        int y0 = (int)y0f, x0 = (int)x0f;
        int y1 = min(y0 + 1, 127), x1 = min(x0 + 1, 127);
        float w00 = (1.f - wy) * (1.f - wx), w01 = (1.f - wy) * wx;
        float w10 = wy * (1.f - wx),         w11 = wy * wx;
        int i00 = (y0 << 7) + x0, i01 = (y0 << 7) + x1;
        int i10 = (y1 << 7) + x0, i11 = (y1 << 7) + x1;

        const float* xb = x + (size_t)(((b << 6) + (wv << 4))) * 16384;
#pragma unroll
        for (int ci = 0; ci < 16; ++ci) {
            const float* xp = xb + (ci << 14);
            float v = xp[i00] * w00 + xp[i01] * w01 + xp[i10] * w10 + xp[i11] * w11;
            dsm[(wv << 4) + ci][lane] = v;
        }
        __syncthreads();

        // acc[i] += sum_c dsm[c][lane] * w_strip[(o*64+c)*9+k], o = wv + 4*i
        const float* wp = w_strip + wv * 576 + k;
#pragma unroll 8
        for (int c = 0; c < 64; ++c) {
            float dv = dsm[c][lane];
            const float* wc = wp + c * 9;
#pragma unroll
            for (int i = 0; i < 16; ++i)
                acc[i] = fmaf(dv, wc[i * 2304], acc[i]);   // 2304 = 4*576
        }
        __syncthreads();
    }

#pragma unroll
    for (int i = 0; i < 16; ++i) {
        int o = wv + (i << 2);
        float v = acc[i] + b_strip[o];
        out[(((b << 6) + o) << 14) + p] = v;
        float s1 = v, s2 = v * v;
#pragma unroll
        for (int d = 32; d; d >>= 1) { s1 += __shfl_down(s1, d, 64); s2 += __shfl_down(s2, d, 64); }
        if (lane == 0) {
            atomicAdd(&out_stats[(b << 6) + o], s1);
            atomicAdd(&out_stats[256 + (b << 6) + o], s2);
        }
    }
}

// ---------------------------------------------------------------------------
// Kernel 3: output GroupNorm (16 groups of 4 channels) + ReLU, in place.
// ---------------------------------------------------------------------------
__global__ __launch_bounds__(256) void k_gn_out(
    float* __restrict__ out, const float* __restrict__ out_stats,
    const float* __restrict__ gg, const float* __restrict__ gb)
{
    const float inv_cnt = 1.f / (4.f * 16384.f);
    const int n4 = 1 << 20;   // 4.19M floats / 4
    for (int idx = blockIdx.x * 256 + threadIdx.x; idx < n4; idx += gridDim.x * 256) {
        int flat = idx << 2;
        int ch = (flat >> 14) & 63;
        int b  = flat >> 20;
        int cb = (b << 6) + ((ch >> 2) << 2);
        float s = out_stats[cb] + out_stats[cb + 1] + out_stats[cb + 2] + out_stats[cb + 3];
        float q = out_stats[256 + cb] + out_stats[256 + cb + 1] + out_stats[256 + cb + 2] + out_stats[256 + cb + 3];
        float mu   = s * inv_cnt;
        float istd = rsqrtf(fmaxf(q * inv_cnt - mu * mu, 0.f) + 1e-5f);
        float ga = gg[ch] * istd;
        float be = gb[ch] - mu * ga;
        float4 v = *reinterpret_cast<float4*>(out + flat);
        v.x = fmaxf(fmaf(v.x, ga, be), 0.f);
        v.y = fmaxf(fmaf(v.y, ga, be), 0.f);
        v.z = fmaxf(fmaf(v.z, ga, be), 0.f);
        v.w = fmaxf(fmaf(v.w, ga, be), 0.f);
        *reinterpret_cast<float4*>(out + flat) = v;
    }
}

// ---------------------------------------------------------------------------
extern "C" void kernel_launch(void* const* d_in, const int* in_sizes, int n_in,
                              void* d_out, int out_size, void* d_ws, size_t ws_size,
                              hipStream_t stream)
{
    const float* x       = (const float*)d_in[0];
    const float* w_off   = (const float*)d_in[1];
    const float* b_off   = (const float*)d_in[2];
    const float* w_th    = (const float*)d_in[3];
    const float* b_th    = (const float*)d_in[4];
    const float* g_off   = (const float*)d_in[5];
    const float* be_off  = (const float*)d_in[6];
    const float* g_th    = (const float*)d_in[7];
    const float* be_th   = (const float*)d_in[8];
    const float* w_strip = (const float*)d_in[9];
    const float* b_strip = (const float*)d_in[10];
    const float* gg      = (const float*)d_in[11];
    const float* gb      = (const float*)d_in[12];

    float* out      = (float*)d_out;
    float* ws       = (float*)d_ws;
    float* off_raw  = ws;                 // 4*9*16384 = 589824 floats
    float* th_raw   = ws + 589824;        // 589824 floats
    float* stats    = ws + 1179648;       // 144 floats (off/th sum & sumsq)
    float* out_stats = stats + 144;       // 512 floats (out sum & sumsq)

    hipMemsetAsync(stats, 0, 656 * sizeof(float), stream);

    dim3 g1(8, 8, 4);
    k_conv<<<g1, 256, 0, stream>>>(x, w_off, b_off, w_th, b_th, off_raw, th_raw, stats);
    k_sample_strip<<<1024, 256, 0, stream>>>(x, off_raw, th_raw, stats,
                                             g_off, be_off, g_th, be_th,
                                             w_strip, b_strip, out, out_stats);
    k_gn_out<<<2048, 256, 0, stream>>>(out, out_stats, gg, gb);
}

// Round 2
// 403.199 us; speedup vs baseline: 1.8561x; 1.8561x over previous
//
#include <hip/hip_runtime.h>
#include <math.h>

// Problem constants: B=4, C=64, H=128, W=128, K=9, O=64

__device__ __forceinline__ float fast_tanh(float a) {
    float aa = fabsf(a);
    float e = __expf(2.f * aa);
    float t = 1.f - 2.f / (e + 1.f);   // e==inf -> t = 1
    return copysignf(t, a);
}

// ---------------------------------------------------------------------------
// Kernel 1: fused 3x3 conv (off) + 5x5 conv (theta), channel-split 4-way,
// atomicAdd accumulation into off_raw/th_raw (pre-zeroed).
// grid (8,8,16): z = b*4 + split. block 256 (16x16 pixel tile).
// ---------------------------------------------------------------------------
__global__ __launch_bounds__(256, 4) void k_conv(
    const float* __restrict__ x,
    const float* __restrict__ w_off, const float* __restrict__ b_off,
    const float* __restrict__ w_th,  const float* __restrict__ b_th,
    float* __restrict__ off_raw, float* __restrict__ th_raw)
{
    __shared__ float tile[20][20];
    const int t  = threadIdx.x;
    const int tx = t & 15, ty = t >> 4;
    const int z  = blockIdx.z;
    const int b  = z >> 2, sp = z & 3;
    const int c0 = sp << 4;
    const int h0 = blockIdx.y << 4, w0 = blockIdx.x << 4;

    float accO[9], accT[9];
#pragma unroll
    for (int k = 0; k < 9; ++k) { accO[k] = 0.f; accT[k] = 0.f; }

    for (int ci = 0; ci < 16; ++ci) {
        const int c = c0 + ci;
        __syncthreads();
        const float* xp = x + (((b << 6) + c) << 14);
        for (int e = t; e < 400; e += 256) {
            int r = e / 20, cc = e - r * 20;
            int hh = h0 + r - 2, ww = w0 + cc - 2;
            tile[r][cc] = (hh >= 0 && hh < 128 && ww >= 0 && ww < 128)
                            ? xp[(hh << 7) + ww] : 0.f;
        }
        __syncthreads();

        float win[5][5];
#pragma unroll
        for (int i = 0; i < 5; ++i)
#pragma unroll
            for (int j = 0; j < 5; ++j)
                win[i][j] = tile[ty + i][tx + j];

#pragma unroll
        for (int k = 0; k < 9; ++k) {
            const float* wo = w_off + (size_t)((k << 6) + c) * 9;
            float a = accO[k];
#pragma unroll
            for (int i = 0; i < 3; ++i)
#pragma unroll
                for (int j = 0; j < 3; ++j)
                    a = fmaf(win[i + 1][j + 1], wo[i * 3 + j], a);
            accO[k] = a;

            const float* wt = w_th + (size_t)((k << 6) + c) * 25;
            float bb = accT[k];
#pragma unroll
            for (int i = 0; i < 5; ++i)
#pragma unroll
                for (int j = 0; j < 5; ++j)
                    bb = fmaf(win[i][j], wt[i * 5 + j], bb);
            accT[k] = bb;
        }
    }

    const int pix = ((h0 + ty) << 7) + (w0 + tx);
#pragma unroll
    for (int k = 0; k < 9; ++k) {
        float vo = accO[k] + (sp == 0 ? b_off[k] : 0.f);
        float vt = accT[k] + (sp == 0 ? b_th[k]  : 0.f);
        atomicAdd(&off_raw[((b * 9 + k) << 14) + pix], vo);
        atomicAdd(&th_raw [((b * 9 + k) << 14) + pix], vt);
    }
}

// ---------------------------------------------------------------------------
// Kernel 1b: GN stats (sum, sumsq) per (b,k) for off and theta maps.
// grid 72 (= 2 arrays * 36 (b,k) pairs), block 256.
// ---------------------------------------------------------------------------
__global__ __launch_bounds__(256) void k_stats(
    const float* __restrict__ off_raw, const float* __restrict__ th_raw,
    float* __restrict__ stats)
{
    const int id  = blockIdx.x;          // 0..71
    const int arr = id >= 36;
    const int rem = id - arr * 36;       // b*9+k
    const float4* src = (const float4*)((arr ? th_raw : off_raw) + (rem << 14));

    float s1 = 0.f, s2 = 0.f;
    for (int i = threadIdx.x; i < 4096; i += 256) {
        float4 v = src[i];
        s1 += v.x + v.y + v.z + v.w;
        s2 += v.x * v.x + v.y * v.y + v.z * v.z + v.w * v.w;
    }
#pragma unroll
    for (int d = 32; d; d >>= 1) { s1 += __shfl_down(s1, d, 64); s2 += __shfl_down(s2, d, 64); }

    __shared__ float ls1[4], ls2[4];
    const int wv = threadIdx.x >> 6;
    if ((threadIdx.x & 63) == 0) { ls1[wv] = s1; ls2[wv] = s2; }
    __syncthreads();
    if (threadIdx.x == 0) {
        float a = ls1[0] + ls1[1] + ls1[2] + ls1[3];
        float q = ls2[0] + ls2[1] + ls2[2] + ls2[3];
        stats[arr * 72 + rem]      = a;
        stats[arr * 72 + 36 + rem] = q;
    }
}

// ---------------------------------------------------------------------------
// Kernel 2: deformable bilinear sample + strip contraction + output GN stats.
// grid 1024 (= B * 256), block 256, XCD-chunked block swizzle for L2 locality.
// ---------------------------------------------------------------------------
__global__ __launch_bounds__(256) void k_sample_strip(
    const float* __restrict__ x,
    const float* __restrict__ off_raw, const float* __restrict__ th_raw,
    const float* __restrict__ stats,
    const float* __restrict__ g_off, const float* __restrict__ be_off,
    const float* __restrict__ g_th,  const float* __restrict__ be_th,
    const float* __restrict__ w_strip, const float* __restrict__ b_strip,
    float* __restrict__ out, float* __restrict__ out_stats)
{
    __shared__ float dsm[64][65];
    const int t    = threadIdx.x;
    const int lane = t & 63;
    const int wv   = __builtin_amdgcn_readfirstlane(t >> 6);
    // XCD-chunked swizzle: consecutive logical blocks land on the same XCD.
    const int bid  = blockIdx.x;
    const int blk  = ((bid & 7) << 7) + (bid >> 3);
    const int b    = blk >> 8;
    const int p    = ((blk & 255) << 6) + lane;
    const int h    = p >> 7, w = p & 127;

    float muO[3], isO[3], muT[3], isT[3];
    const float inv_cnt = 1.f / (3.f * 16384.f);
#pragma unroll
    for (int g = 0; g < 3; ++g) {
        float s = 0.f, q = 0.f;
#pragma unroll
        for (int j = 0; j < 3; ++j) { s += stats[b * 9 + 3 * g + j]; q += stats[36 + b * 9 + 3 * g + j]; }
        float mu = s * inv_cnt;
        muO[g] = mu; isO[g] = rsqrtf(fmaxf(q * inv_cnt - mu * mu, 0.f) + 1e-5f);
        s = 0.f; q = 0.f;
#pragma unroll
        for (int j = 0; j < 3; ++j) { s += stats[72 + b * 9 + 3 * g + j]; q += stats[108 + b * 9 + 3 * g + j]; }
        mu = s * inv_cnt;
        muT[g] = mu; isT[g] = rsqrtf(fmaxf(q * inv_cnt - mu * mu, 0.f) + 1e-5f);
    }

    float acc[16];
#pragma unroll
    for (int i = 0; i < 16; ++i) acc[i] = 0.f;

    for (int k = 0; k < 9; ++k) {
        const int s = k - 4;
        const int m = 4 + (s < 0 ? -s : s);
        float yy, xx;
        if (k == 4) {
            yy = (float)h; xx = (float)w;
        } else {
            const int g = m / 3;
            float z = (th_raw[((b * 9 + m) << 14) + p] - muT[g]) * isT[g] * g_th[m] + be_th[m];
            float f = fast_tanh((off_raw[((b * 9 + m) << 14) + p] - muO[g]) * isO[g] * g_off[m] + be_off[m]);
            float r = rsqrtf(1.f + z * z);     // cos(arctan z); sin = z*r; tan = z
            float fs = (float)s;
            yy = (float)h + fs + (fs * z + f * r);
            xx = (float)w + fs + (fs - z * r * f);
            yy = fminf(fmaxf(yy, 0.f), 127.f);
            xx = fminf(fmaxf(xx, 0.f), 127.f);
        }
        float y0f = floorf(yy), x0f = floorf(xx);
        float wy = yy - y0f, wx = xx - x0f;
        int y0 = (int)y0f, x0 = (int)x0f;
        int y1 = min(y0 + 1, 127), x1 = min(x0 + 1, 127);
        float w00 = (1.f - wy) * (1.f - wx), w01 = (1.f - wy) * wx;
        float w10 = wy * (1.f - wx),         w11 = wy * wx;
        int i00 = (y0 << 7) + x0, i01 = (y0 << 7) + x1;
        int i10 = (y1 << 7) + x0, i11 = (y1 << 7) + x1;

        const float* xb = x + (size_t)(((b << 6) + (wv << 4))) * 16384;
#pragma unroll
        for (int ci = 0; ci < 16; ++ci) {
            const float* xp = xb + (ci << 14);
            float v = xp[i00] * w00 + xp[i01] * w01 + xp[i10] * w10 + xp[i11] * w11;
            dsm[(wv << 4) + ci][lane] = v;
        }
        __syncthreads();

        const float* wp = w_strip + wv * 576 + k;
#pragma unroll 8
        for (int c = 0; c < 64; ++c) {
            float dv = dsm[c][lane];
            const float* wc = wp + c * 9;
#pragma unroll
            for (int i = 0; i < 16; ++i)
                acc[i] = fmaf(dv, wc[i * 2304], acc[i]);   // 2304 = 4*576
        }
        __syncthreads();
    }

#pragma unroll
    for (int i = 0; i < 16; ++i) {
        int o = wv + (i << 2);
        float v = acc[i] + b_strip[o];
        out[(((b << 6) + o) << 14) + p] = v;
        float s1 = v, s2 = v * v;
#pragma unroll
        for (int d = 32; d; d >>= 1) { s1 += __shfl_down(s1, d, 64); s2 += __shfl_down(s2, d, 64); }
        if (lane == 0) {
            atomicAdd(&out_stats[(b << 6) + o], s1);
            atomicAdd(&out_stats[256 + (b << 6) + o], s2);
        }
    }
}

// ---------------------------------------------------------------------------
// Kernel 3: output GroupNorm (16 groups of 4 channels) + ReLU, in place.
// ---------------------------------------------------------------------------
__global__ __launch_bounds__(256) void k_gn_out(
    float* __restrict__ out, const float* __restrict__ out_stats,
    const float* __restrict__ gg, const float* __restrict__ gb)
{
    const float inv_cnt = 1.f / (4.f * 16384.f);
    const int n4 = 1 << 20;
    for (int idx = blockIdx.x * 256 + threadIdx.x; idx < n4; idx += gridDim.x * 256) {
        int flat = idx << 2;
        int ch = (flat >> 14) & 63;
        int b  = flat >> 20;
        int cb = (b << 6) + ((ch >> 2) << 2);
        float s = out_stats[cb] + out_stats[cb + 1] + out_stats[cb + 2] + out_stats[cb + 3];
        float q = out_stats[256 + cb] + out_stats[256 + cb + 1] + out_stats[256 + cb + 2] + out_stats[256 + cb + 3];
        float mu   = s * inv_cnt;
        float istd = rsqrtf(fmaxf(q * inv_cnt - mu * mu, 0.f) + 1e-5f);
        float ga = gg[ch] * istd;
        float be = gb[ch] - mu * ga;
        float4 v = *reinterpret_cast<float4*>(out + flat);
        v.x = fmaxf(fmaf(v.x, ga, be), 0.f);
        v.y = fmaxf(fmaf(v.y, ga, be), 0.f);
        v.z = fmaxf(fmaf(v.z, ga, be), 0.f);
        v.w = fmaxf(fmaf(v.w, ga, be), 0.f);
        *reinterpret_cast<float4*>(out + flat) = v;
    }
}

// ---------------------------------------------------------------------------
extern "C" void kernel_launch(void* const* d_in, const int* in_sizes, int n_in,
                              void* d_out, int out_size, void* d_ws, size_t ws_size,
                              hipStream_t stream)
{
    const float* x       = (const float*)d_in[0];
    const float* w_off   = (const float*)d_in[1];
    const float* b_off   = (const float*)d_in[2];
    const float* w_th    = (const float*)d_in[3];
    const float* b_th    = (const float*)d_in[4];
    const float* g_off   = (const float*)d_in[5];
    const float* be_off  = (const float*)d_in[6];
    const float* g_th    = (const float*)d_in[7];
    const float* be_th   = (const float*)d_in[8];
    const float* w_strip = (const float*)d_in[9];
    const float* b_strip = (const float*)d_in[10];
    const float* gg      = (const float*)d_in[11];
    const float* gb      = (const float*)d_in[12];

    float* out       = (float*)d_out;
    float* ws        = (float*)d_ws;
    float* off_raw   = ws;                 // 589824 floats
    float* th_raw    = ws + 589824;        // 589824 floats
    float* stats     = ws + 1179648;       // 144 floats
    float* out_stats = stats + 144;        // 512 floats

    // zero off_raw, th_raw (atomic accumulation targets) + stats + out_stats
    hipMemsetAsync(ws, 0, (size_t)(1179648 + 656) * sizeof(float), stream);

    dim3 g1(8, 8, 16);
    k_conv<<<g1, 256, 0, stream>>>(x, w_off, b_off, w_th, b_th, off_raw, th_raw);
    k_stats<<<72, 256, 0, stream>>>(off_raw, th_raw, stats);
    k_sample_strip<<<1024, 256, 0, stream>>>(x, off_raw, th_raw, stats,
                                             g_off, be_off, g_th, be_th,
                                             w_strip, b_strip, out, out_stats);
    k_gn_out<<<2048, 256, 0, stream>>>(out, out_stats, gg, gb);
}

// Round 3
// 187.353 us; speedup vs baseline: 3.9945x; 2.1521x over previous
//
#include <hip/hip_runtime.h>
#include <math.h>

// Problem constants: B=4, C=64, H=128, W=128, K=9, O=64

typedef short v8s __attribute__((ext_vector_type(8)));
typedef float v4f __attribute__((ext_vector_type(4)));

__device__ __forceinline__ float fast_tanh(float a) {
    float aa = fabsf(a);
    float e = __expf(2.f * aa);
    float t = 1.f - 2.f / (e + 1.f);   // e==inf -> t = 1
    return copysignf(t, a);
}

// ---------------------------------------------------------------------------
// Kernel 0: prepack w_strip into bf16 A-fragment order.
// w_pack[(((k*4+wv)*2+kk)*64 + lane)*8 + j] = bf16( w[(o*64+c)*9+k] )
//   with o = wv*16 + (lane&15), c = kk*32 + (lane>>4)*8 + j.
// grid 144, block 256 (36864 elements).
// ---------------------------------------------------------------------------
__global__ __launch_bounds__(256) void k_pack(
    const float* __restrict__ w_strip, short* __restrict__ w_pack)
{
    int idx = blockIdx.x * 256 + threadIdx.x;
    int j    = idx & 7;
    int lane = (idx >> 3) & 63;
    int kk   = (idx >> 9) & 1;
    int wv   = (idx >> 10) & 3;
    int k    = idx >> 12;
    int c = (kk << 5) + ((lane >> 4) << 3) + j;
    int o = (wv << 4) + (lane & 15);
    union { short s; __bf16 h; } u;
    u.h = (__bf16)w_strip[(o * 64 + c) * 9 + k];
    w_pack[idx] = u.s;
}

// ---------------------------------------------------------------------------
// Kernel 1: fused 3x3 conv (off) + 5x5 conv (theta), channel-split 8-way,
// atomicAdd accumulation into off_raw/th_raw (pre-zeroed).
// grid (8,8,32): z = b*8 + split. block 256 (16x16 pixel tile).
// ---------------------------------------------------------------------------
__global__ __launch_bounds__(256, 8) void k_conv(
    const float* __restrict__ x,
    const float* __restrict__ w_off, const float* __restrict__ b_off,
    const float* __restrict__ w_th,  const float* __restrict__ b_th,
    float* __restrict__ off_raw, float* __restrict__ th_raw)
{
    __shared__ float tile[20][20];
    const int t  = threadIdx.x;
    const int tx = t & 15, ty = t >> 4;
    const int z  = blockIdx.z;
    const int b  = z >> 3, sp = z & 7;
    const int c0 = sp << 3;
    const int h0 = blockIdx.y << 4, w0 = blockIdx.x << 4;

    float accO[9], accT[9];
#pragma unroll
    for (int k = 0; k < 9; ++k) { accO[k] = 0.f; accT[k] = 0.f; }

    for (int ci = 0; ci < 8; ++ci) {
        const int c = c0 + ci;
        __syncthreads();
        const float* xp = x + (((b << 6) + c) << 14);
        for (int e = t; e < 400; e += 256) {
            int r = e / 20, cc = e - r * 20;
            int hh = h0 + r - 2, ww = w0 + cc - 2;
            tile[r][cc] = (hh >= 0 && hh < 128 && ww >= 0 && ww < 128)
                            ? xp[(hh << 7) + ww] : 0.f;
        }
        __syncthreads();

        float win[5][5];
#pragma unroll
        for (int i = 0; i < 5; ++i)
#pragma unroll
            for (int j = 0; j < 5; ++j)
                win[i][j] = tile[ty + i][tx + j];

#pragma unroll
        for (int k = 0; k < 9; ++k) {
            const float* wo = w_off + (size_t)((k << 6) + c) * 9;
            float a = accO[k];
#pragma unroll
            for (int i = 0; i < 3; ++i)
#pragma unroll
                for (int j = 0; j < 3; ++j)
                    a = fmaf(win[i + 1][j + 1], wo[i * 3 + j], a);
            accO[k] = a;

            const float* wt = w_th + (size_t)((k << 6) + c) * 25;
            float bb = accT[k];
#pragma unroll
            for (int i = 0; i < 5; ++i)
#pragma unroll
                for (int j = 0; j < 5; ++j)
                    bb = fmaf(win[i][j], wt[i * 5 + j], bb);
            accT[k] = bb;
        }
    }

    const int pix = ((h0 + ty) << 7) + (w0 + tx);
#pragma unroll
    for (int k = 0; k < 9; ++k) {
        float vo = accO[k] + (sp == 0 ? b_off[k] : 0.f);
        float vt = accT[k] + (sp == 0 ? b_th[k]  : 0.f);
        atomicAdd(&off_raw[((b * 9 + k) << 14) + pix], vo);
        atomicAdd(&th_raw [((b * 9 + k) << 14) + pix], vt);
    }
}

// ---------------------------------------------------------------------------
// Kernel 1b: GN stats (sum, sumsq) per (b,k) for off and theta maps.
// ---------------------------------------------------------------------------
__global__ __launch_bounds__(256) void k_stats(
    const float* __restrict__ off_raw, const float* __restrict__ th_raw,
    float* __restrict__ stats)
{
    const int id  = blockIdx.x;          // 0..71
    const int arr = id >= 36;
    const int rem = id - arr * 36;       // b*9+k
    const float4* src = (const float4*)((arr ? th_raw : off_raw) + (rem << 14));

    float s1 = 0.f, s2 = 0.f;
    for (int i = threadIdx.x; i < 4096; i += 256) {
        float4 v = src[i];
        s1 += v.x + v.y + v.z + v.w;
        s2 += v.x * v.x + v.y * v.y + v.z * v.z + v.w * v.w;
    }
#pragma unroll
    for (int d = 32; d; d >>= 1) { s1 += __shfl_down(s1, d, 64); s2 += __shfl_down(s2, d, 64); }

    __shared__ float ls1[4], ls2[4];
    const int wv = threadIdx.x >> 6;
    if ((threadIdx.x & 63) == 0) { ls1[wv] = s1; ls2[wv] = s2; }
    __syncthreads();
    if (threadIdx.x == 0) {
        float a = ls1[0] + ls1[1] + ls1[2] + ls1[3];
        float q = ls2[0] + ls2[1] + ls2[2] + ls2[3];
        stats[arr * 72 + rem]      = a;
        stats[arr * 72 + 36 + rem] = q;
    }
}

// ---------------------------------------------------------------------------
// Kernel 2: deformable bilinear sample (fp32) -> bf16 LDS tile -> MFMA strip
// contraction. grid 1024 (B*256 half-rows), block 256 (4 waves), XCD swizzle.
// Per block: 64 pixels. Wave wv gathers channels [wv*16, wv*16+16); MFMA:
// each wave computes out[o in wv*16..+16][all 64 p], K-dim = 64 channels.
// LDS: bf16 d[p][c], 64x64, 16B blocks rotated by row for bank spread.
// ---------------------------------------------------------------------------
__global__ __launch_bounds__(256) void k_sample_strip(
    const float* __restrict__ x,
    const float* __restrict__ off_raw, const float* __restrict__ th_raw,
    const float* __restrict__ stats,
    const float* __restrict__ g_off, const float* __restrict__ be_off,
    const float* __restrict__ g_th,  const float* __restrict__ be_th,
    const short* __restrict__ w_pack, const float* __restrict__ b_strip,
    float* __restrict__ out)
{
    __shared__ __align__(16) short smem[64 * 64];
    const int t    = threadIdx.x;
    const int lane = t & 63;
    const int wv   = __builtin_amdgcn_readfirstlane(t >> 6);
    const int bid  = blockIdx.x;
    const int blk  = ((bid & 7) << 7) + (bid >> 3);   // XCD-chunked swizzle
    const int b    = blk >> 8;
    const int pix0 = (blk & 255) << 6;
    const int p    = pix0 + lane;
    const int h    = p >> 7, w = p & 127;
    const int i15  = lane & 15, lg = lane >> 4;

    // GroupNorm constants for off/theta (redundant per thread; tiny)
    float muO[3], isO[3], muT[3], isT[3];
    const float inv_cnt = 1.f / (3.f * 16384.f);
#pragma unroll
    for (int g = 0; g < 3; ++g) {
        float s = 0.f, q = 0.f;
#pragma unroll
        for (int j = 0; j < 3; ++j) { s += stats[b * 9 + 3 * g + j]; q += stats[36 + b * 9 + 3 * g + j]; }
        float mu = s * inv_cnt;
        muO[g] = mu; isO[g] = rsqrtf(fmaxf(q * inv_cnt - mu * mu, 0.f) + 1e-5f);
        s = 0.f; q = 0.f;
#pragma unroll
        for (int j = 0; j < 3; ++j) { s += stats[72 + b * 9 + 3 * g + j]; q += stats[108 + b * 9 + 3 * g + j]; }
        mu = s * inv_cnt;
        muT[g] = mu; isT[g] = rsqrtf(fmaxf(q * inv_cnt - mu * mu, 0.f) + 1e-5f);
    }

    const float* xb = x + ((size_t)((b << 6) + (wv << 4)) << 14);

    v4f acc[4];
#pragma unroll
    for (int n = 0; n < 4; ++n) acc[n] = (v4f)0.f;

    for (int k = 0; k < 9; ++k) {
        float v[16];
        if (k == 4) {
#pragma unroll
            for (int ci = 0; ci < 16; ++ci) v[ci] = xb[(ci << 14) + p];
        } else {
            const int s = k - 4;
            const int m = 4 + (s < 0 ? -s : s);
            const int g = m / 3;
            float z = (th_raw[((b * 9 + m) << 14) + p] - muT[g]) * isT[g] * g_th[m] + be_th[m];
            float f = fast_tanh((off_raw[((b * 9 + m) << 14) + p] - muO[g]) * isO[g] * g_off[m] + be_off[m]);
            float r = rsqrtf(1.f + z * z);     // cos(arctan z); sin = z*r; tan = z
            float fs = (float)s;
            float yy = (float)h + fs + fs * z + f * r;
            float xx = (float)w + fs + fs - z * r * f;
            yy = fminf(fmaxf(yy, 0.f), 127.f);
            xx = fminf(fmaxf(xx, 0.f), 127.f);
            // clamp-free bilinear: y0,x0 <= 126, weights absorb the edge
            int y0 = min((int)yy, 126);
            int x0 = min((int)xx, 126);
            float wy = yy - (float)y0;
            float wx = xx - (float)x0;
            const float* base = xb + (y0 << 7) + x0;
#pragma unroll
            for (int ci = 0; ci < 16; ++ci) {
                const float* q = base + (ci << 14);
                float2 r0 = *(const float2*)q;
                float2 r1 = *(const float2*)(q + 128);
                float lo = fmaf(wx, r0.y - r0.x, r0.x);
                float hi = fmaf(wx, r1.y - r1.x, r1.x);
                v[ci] = fmaf(wy, hi - lo, lo);
            }
        }

        // pack to bf16, store to LDS with row-rotated 16B blocks
        union { v8s s8; __bf16 hh[8]; } u0, u1;
#pragma unroll
        for (int ci = 0; ci < 8; ++ci) { u0.hh[ci] = (__bf16)v[ci]; u1.hh[ci] = (__bf16)v[ci + 8]; }
        *(v8s*)&smem[(lane << 6) + ((((wv << 1) + 0) + lane) & 7) * 8] = u0.s8;
        *(v8s*)&smem[(lane << 6) + ((((wv << 1) + 1) + lane) & 7) * 8] = u1.s8;
        __syncthreads();

        // A fragments (prepacked, coalesced 16B/lane)
        const short* wpk = w_pack + (((k << 2) + wv) << 10) + (lane << 3);
        v8s a0 = *(const v8s*)wpk;
        v8s a1 = *(const v8s*)(wpk + 512);

#pragma unroll
        for (int n = 0; n < 4; ++n) {
            int r = (n << 4) + i15;
            v8s b0 = *(const v8s*)&smem[(r << 6) + (((lg    ) + r) & 7) * 8];
            v8s b1 = *(const v8s*)&smem[(r << 6) + (((lg + 4) + r) & 7) * 8];
            acc[n] = __builtin_amdgcn_mfma_f32_16x16x32_bf16(a0, b0, acc[n], 0, 0, 0);
            acc[n] = __builtin_amdgcn_mfma_f32_16x16x32_bf16(a1, b1, acc[n], 0, 0, 0);
        }
        __syncthreads();
    }

    // epilogue: D layout col=lane&15, row=(lane>>4)*4+reg
#pragma unroll
    for (int r = 0; r < 4; ++r) {
        int o = (wv << 4) + (lg << 2) + r;
        float bias = b_strip[o];
        float* op = out + ((size_t)((b << 6) + o) << 14) + pix0 + i15;
#pragma unroll
        for (int n = 0; n < 4; ++n)
            op[n << 4] = acc[n][r] + bias;
    }
}

// ---------------------------------------------------------------------------
// Kernel 2b: output GN stats per (b,o). grid 256, block 256.
// ---------------------------------------------------------------------------
__global__ __launch_bounds__(256) void k_stats_out(
    const float* __restrict__ out, float* __restrict__ out_stats)
{
    const int bo = blockIdx.x;
    const float4* src = (const float4*)(out + ((size_t)bo << 14));
    float s1 = 0.f, s2 = 0.f;
    for (int i = threadIdx.x; i < 4096; i += 256) {
        float4 v = src[i];
        s1 += v.x + v.y + v.z + v.w;
        s2 += v.x * v.x + v.y * v.y + v.z * v.z + v.w * v.w;
    }
#pragma unroll
    for (int d = 32; d; d >>= 1) { s1 += __shfl_down(s1, d, 64); s2 += __shfl_down(s2, d, 64); }

    __shared__ float ls1[4], ls2[4];
    const int wv = threadIdx.x >> 6;
    if ((threadIdx.x & 63) == 0) { ls1[wv] = s1; ls2[wv] = s2; }
    __syncthreads();
    if (threadIdx.x == 0) {
        out_stats[bo]       = ls1[0] + ls1[1] + ls1[2] + ls1[3];
        out_stats[256 + bo] = ls2[0] + ls2[1] + ls2[2] + ls2[3];
    }
}

// ---------------------------------------------------------------------------
// Kernel 3: output GroupNorm (16 groups of 4 channels) + ReLU, in place.
// ---------------------------------------------------------------------------
__global__ __launch_bounds__(256) void k_gn_out(
    float* __restrict__ out, const float* __restrict__ out_stats,
    const float* __restrict__ gg, const float* __restrict__ gb)
{
    const float inv_cnt = 1.f / (4.f * 16384.f);
    const int n4 = 1 << 20;
    for (int idx = blockIdx.x * 256 + threadIdx.x; idx < n4; idx += gridDim.x * 256) {
        int flat = idx << 2;
        int ch = (flat >> 14) & 63;
        int b  = flat >> 20;
        int cb = (b << 6) + ((ch >> 2) << 2);
        float s = out_stats[cb] + out_stats[cb + 1] + out_stats[cb + 2] + out_stats[cb + 3];
        float q = out_stats[256 + cb] + out_stats[256 + cb + 1] + out_stats[256 + cb + 2] + out_stats[256 + cb + 3];
        float mu   = s * inv_cnt;
        float istd = rsqrtf(fmaxf(q * inv_cnt - mu * mu, 0.f) + 1e-5f);
        float ga = gg[ch] * istd;
        float be = gb[ch] - mu * ga;
        float4 v = *reinterpret_cast<float4*>(out + flat);
        v.x = fmaxf(fmaf(v.x, ga, be), 0.f);
        v.y = fmaxf(fmaf(v.y, ga, be), 0.f);
        v.z = fmaxf(fmaf(v.z, ga, be), 0.f);
        v.w = fmaxf(fmaf(v.w, ga, be), 0.f);
        *reinterpret_cast<float4*>(out + flat) = v;
    }
}

// ---------------------------------------------------------------------------
extern "C" void kernel_launch(void* const* d_in, const int* in_sizes, int n_in,
                              void* d_out, int out_size, void* d_ws, size_t ws_size,
                              hipStream_t stream)
{
    const float* x       = (const float*)d_in[0];
    const float* w_off   = (const float*)d_in[1];
    const float* b_off   = (const float*)d_in[2];
    const float* w_th    = (const float*)d_in[3];
    const float* b_th    = (const float*)d_in[4];
    const float* g_off   = (const float*)d_in[5];
    const float* be_off  = (const float*)d_in[6];
    const float* g_th    = (const float*)d_in[7];
    const float* be_th   = (const float*)d_in[8];
    const float* w_strip = (const float*)d_in[9];
    const float* b_strip = (const float*)d_in[10];
    const float* gg      = (const float*)d_in[11];
    const float* gb      = (const float*)d_in[12];

    float* out       = (float*)d_out;
    float* ws        = (float*)d_ws;
    float* off_raw   = ws;                    // 589824 floats
    float* th_raw    = ws + 589824;           // 589824 floats
    float* stats     = ws + 1179648;          // 144 floats
    float* out_stats = ws + 1179792;          // 512 floats
    short* w_pack    = (short*)(ws + 1180304); // 36864 shorts (16B-aligned)

    // zero only the atomic accumulation targets
    hipMemsetAsync(ws, 0, (size_t)1179648 * sizeof(float), stream);

    k_pack<<<144, 256, 0, stream>>>(w_strip, w_pack);
    dim3 g1(8, 8, 32);
    k_conv<<<g1, 256, 0, stream>>>(x, w_off, b_off, w_th, b_th, off_raw, th_raw);
    k_stats<<<72, 256, 0, stream>>>(off_raw, th_raw, stats);
    k_sample_strip<<<1024, 256, 0, stream>>>(x, off_raw, th_raw, stats,
                                             g_off, be_off, g_th, be_th,
                                             w_pack, b_strip, out);
    k_stats_out<<<256, 256, 0, stream>>>(out, out_stats);
    k_gn_out<<<2048, 256, 0, stream>>>(out, out_stats, gg, gb);
}